// Round 16
// baseline (429.382 us; speedup 1.0000x reference)
//
#include <hip/hip_runtime.h>
#include <hip/hip_fp16.h>
#include <math.h>

#define NN 100000
#define NE 1000000
#define CAP 32        // bucket capacity per node; degrees ~Poisson(10), max ~27
#define OVCAP 4096    // overflow list capacity (correct fallback, ~never used)
#define NEB 3907      // ceil(NE/256) bucket blocks
#define NTILE 6250    // NN/16 MFMA row-tiles
#define RB 256        // softmax reduction grid
#define NSLICE 4      // src-range slices: 25000 nodes = 3.2MB fp16 rows, fits XCD L2
#define SLICEW 25000
// H = 64. Features stored fp16 with dinv[src] PRE-FOLDED: xw'[i] = dinv[i]*(X@W)[i].
// Gather: acc = sum_e ew*xw'[src] + xw'[self]; out = acc*dinv[dst].
// R14 LESSON: gather input and GEMM output must be DISTINCT buffers.
// R16: gathers loop over src slices so the hot row set fits per-XCD L2
// (R7/R12 counters: gathers are L2-miss line-rate bound to L3).

typedef _Float16 half8 __attribute__((ext_vector_type(8)));
typedef float f32x4 __attribute__((ext_vector_type(4)));

// ---------------- bucket build (measured floor ~75us; R10 falsified
// placement fixes: writeback = 1 line/edge, temporal) ----------------

__global__ __launch_bounds__(256) void k_bucket(const int* __restrict__ src,
                                                const int* __restrict__ dst,
                                                const float* __restrict__ ew,
                                                int* __restrict__ cnt,
                                                int2* __restrict__ bucket,
                                                int4* __restrict__ ovf,
                                                int* __restrict__ ovf_n) {
  int e = blockIdx.x * 256 + threadIdx.x;
  if (e < NE) {
    int s = src[e];
    int d = dst[e];
    float w = ew[e];
    int pos = atomicAdd(&cnt[d], 1);
    if (pos < CAP) {
      bucket[d * CAP + pos] = make_int2(s, __float_as_int(w));
    } else {
      int t = atomicAdd(ovf_n, 1);
      if (t < OVCAP) ovf[t] = make_int4(s, d, __float_as_int(w), 0);
    }
  }
}

// ---------------- W staging: fragment layout in LDS (k=(s*32+q*8+j), n=t*16+l15) ----------------

__device__ __forceinline__ void stage_B_lds(const float* __restrict__ W,
                                            _Float16* __restrict__ ldsB) {
  for (int u = threadIdx.x; u < 512; u += 256) {
    int slane = u & 63, ts = u >> 6;
    int t = ts >> 1, s = ts & 1;
    int qq = slane >> 4, ll = slane & 15;
#pragma unroll
    for (int j = 0; j < 8; ++j)
      ldsB[u * 8 + j] = (_Float16)W[(s * 32 + qq * 8 + j) * 64 + t * 16 + ll];
  }
}

// ---------------- degsum helper (all lanes; redundant across q-groups) ----------------

__device__ __forceinline__ float degsum_row(const int* __restrict__ cnt,
                                            const int2* __restrict__ bucket,
                                            const int4* __restrict__ ovf,
                                            const int* __restrict__ ovf_n,
                                            int row) {
  int c = cnt[row];
  int cc = c < CAP ? c : CAP;
  float dsum = 1.0f;  // self-loop
  const int2* bk = bucket + (size_t)row * CAP;
  for (int j = 0; j < cc; ++j) dsum += __int_as_float(bk[j].y);
  if (c > CAP) {
    int on = ovf_n[0]; if (on > OVCAP) on = OVCAP;
    for (int t = 0; t < on; ++t) {
      int4 o = ovf[t];
      if (o.y == row) dsum += __int_as_float(o.z);
    }
  }
  return 1.0f / sqrtf(dsum);
}

// ---------------- GEMM1 + inline degsum: dinv + Y' = dinv*(X@W1), fp16 ----------------
// 16x16x32_f16; A: m=lane&15, k=(lane>>4)*8+j; C/D: col=lane&15, row=q*4+reg
// [m89-verified].

__global__ __launch_bounds__(256) void k_gemm1_dinv(const float* __restrict__ X,
                                                    const float* __restrict__ W,
                                                    const int* __restrict__ cnt,
                                                    const int2* __restrict__ bucket,
                                                    const int4* __restrict__ ovf,
                                                    const int* __restrict__ ovf_n,
                                                    float* __restrict__ dinv,
                                                    __half* __restrict__ Y) {
  __shared__ _Float16 ldsB[4096];
  stage_B_lds(W, ldsB);
  __syncthreads();
  int lane = threadIdx.x & 63;
  int l15 = lane & 15, q = lane >> 4;
  half8 bfr[4][2];
#pragma unroll
  for (int t = 0; t < 4; ++t)
#pragma unroll
    for (int s = 0; s < 2; ++s)
      bfr[t][s] = *(half8*)&ldsB[((t * 2 + s) * 64 + lane) * 8];

  int wid = blockIdx.x * 4 + (threadIdx.x >> 6);
  for (int tile = wid; tile < NTILE; tile += 2048) {
    int row = tile * 16 + l15;
    float di = degsum_row(cnt, bucket, ovf, ovf_n, row);
    if (q == 0) dinv[row] = di;
    f32x4 acc[4] = {{0.f,0.f,0.f,0.f},{0.f,0.f,0.f,0.f},
                    {0.f,0.f,0.f,0.f},{0.f,0.f,0.f,0.f}};
#pragma unroll
    for (int s = 0; s < 2; ++s) {
      const float* ap = X + (size_t)row * 64 + s * 32 + q * 8;
      float4 a0 = *(const float4*)ap;
      float4 a1 = *(const float4*)(ap + 4);
      half8 af;
      af[0] = (_Float16)a0.x; af[1] = (_Float16)a0.y;
      af[2] = (_Float16)a0.z; af[3] = (_Float16)a0.w;
      af[4] = (_Float16)a1.x; af[5] = (_Float16)a1.y;
      af[6] = (_Float16)a1.z; af[7] = (_Float16)a1.w;
#pragma unroll
      for (int t = 0; t < 4; ++t)
        acc[t] = __builtin_amdgcn_mfma_f32_16x16x32_f16(af, bfr[t][s], acc[t], 0, 0, 0);
    }
#pragma unroll
    for (int r = 0; r < 4; ++r) {
      int rw = tile * 16 + q * 4 + r;
      float dv = __shfl(di, q * 4 + r, 64);
#pragma unroll
      for (int t = 0; t < 4; ++t)
        Y[(size_t)rw * 64 + t * 16 + l15] = __float2half(acc[t][r] * dv);
    }
  }
}

// ---------------- src-sliced gather: 16 lanes/node, fp16 rows, dinv pre-folded ----------------
// Slice loop confines the random row set to 3.2MB (one XCD L2). Bucket entries
// are block-local (4KB) -> L1-resident across the 4 rescans.

__device__ __forceinline__ float4 h4load(const __half* p) {
  float2 raw = *(const float2*)p;  // 4 halfs in one dwordx2
  __half2 a = *(__half2*)&raw.x;
  __half2 b = *(__half2*)&raw.y;
  float2 fa = __half22float2(a), fb = __half22float2(b);
  return make_float4(fa.x, fa.y, fb.x, fb.y);
}

__device__ __forceinline__ float4 gather_node(const __half* __restrict__ xw,
                                              const int* __restrict__ cnt,
                                              const int2* __restrict__ bucket,
                                              const int4* __restrict__ ovf,
                                              const int* __restrict__ ovf_n,
                                              int node, int l) {
  int c = cnt[node];
  int cc = c < CAP ? c : CAP;
  const int2* bk = bucket + (size_t)node * CAP;
  float4 acc = make_float4(0.f, 0.f, 0.f, 0.f);

#pragma unroll 1
  for (int sl = 0; sl < NSLICE; ++sl) {
    unsigned lo = sl * SLICEW;
    for (int j = 0; j < cc; ++j) {
      int2 E = bk[j];
      if ((unsigned)(E.x - lo) < (unsigned)SLICEW) {
        const float4 xa = h4load(xw + (size_t)E.x * 64 + l * 4);
        float v = __int_as_float(E.y);
        acc.x = fmaf(xa.x, v, acc.x); acc.y = fmaf(xa.y, v, acc.y);
        acc.z = fmaf(xa.z, v, acc.z); acc.w = fmaf(xa.w, v, acc.w);
      }
    }
  }
  if (c > CAP) {
    int on = ovf_n[0]; if (on > OVCAP) on = OVCAP;
    for (int t = 0; t < on; ++t) {
      int4 o = ovf[t];
      if (o.y == node) {
        const float4 xa = h4load(xw + (size_t)o.x * 64 + l * 4);
        float v = __int_as_float(o.z);
        acc.x = fmaf(xa.x, v, acc.x); acc.y = fmaf(xa.y, v, acc.y);
        acc.z = fmaf(xa.z, v, acc.z); acc.w = fmaf(xa.w, v, acc.w);
      }
    }
  }
  // self-loop: xw'[self] weight 1 (outer *dinv[dst] completes dinv^2)
  const float4 xs = h4load(xw + (size_t)node * 64 + l * 4);
  acc.x += xs.x; acc.y += xs.y; acc.z += xs.z; acc.w += xs.w;
  return acc;
}

// ---------------- fused layer-1 gather + GEMM2 (xw -> xw2) ----------------

__global__ __launch_bounds__(256) void k_gather_gemm2(const __half* __restrict__ xw,
                                                      const float* __restrict__ dinv,
                                                      const int* __restrict__ cnt,
                                                      const int2* __restrict__ bucket,
                                                      const int4* __restrict__ ovf,
                                                      const int* __restrict__ ovf_n,
                                                      const float* __restrict__ b1,
                                                      const float* __restrict__ W2,
                                                      __half* __restrict__ Y) {
  __shared__ _Float16 ldsB[4096];
  __shared__ _Float16 ldsR[16 * 72];
  __shared__ float sdi[16];
  stage_B_lds(W2, ldsB);

  int l = threadIdx.x & 15;
  int g = threadIdx.x >> 4;
  int node = blockIdx.x * 16 + g;
  float4 acc = gather_node(xw, cnt, bucket, ovf, ovf_n, node, l);
  float di = dinv[node];
  const float4 b4 = *(const float4*)(b1 + l * 4);
  _Float16* rp = &ldsR[g * 72 + l * 4];
  rp[0] = (_Float16)fmaxf(fmaf(acc.x, di, b4.x), 0.f);
  rp[1] = (_Float16)fmaxf(fmaf(acc.y, di, b4.y), 0.f);
  rp[2] = (_Float16)fmaxf(fmaf(acc.z, di, b4.z), 0.f);
  rp[3] = (_Float16)fmaxf(fmaf(acc.w, di, b4.w), 0.f);
  if (l == 0) sdi[g] = di;
  __syncthreads();

  int lane = threadIdx.x & 63;
  int l15 = lane & 15, q = lane >> 4;
  int t = threadIdx.x >> 6;  // this wave's col-tile
  half8 a0 = *(half8*)&ldsR[l15 * 72 + q * 8];
  half8 a1 = *(half8*)&ldsR[l15 * 72 + 32 + q * 8];
  half8 bf0 = *(half8*)&ldsB[((t * 2 + 0) * 64 + lane) * 8];
  half8 bf1 = *(half8*)&ldsB[((t * 2 + 1) * 64 + lane) * 8];
  f32x4 acc2 = {0.f, 0.f, 0.f, 0.f};
  acc2 = __builtin_amdgcn_mfma_f32_16x16x32_f16(a0, bf0, acc2, 0, 0, 0);
  acc2 = __builtin_amdgcn_mfma_f32_16x16x32_f16(a1, bf1, acc2, 0, 0, 0);
#pragma unroll
  for (int r = 0; r < 4; ++r) {
    int rw = blockIdx.x * 16 + q * 4 + r;
    float dv = sdi[q * 4 + r];
    Y[(size_t)rw * 64 + t * 16 + l15] = __float2half(acc2[r] * dv);
  }
}

// ---------------- layer-2 aggregation + heads + per-block max partial ----------------

__global__ __launch_bounds__(256) void k_gather_l2_heads(const __half* __restrict__ xw2,
                                                         const float* __restrict__ dinv,
                                                         const int* __restrict__ cnt,
                                                         const int2* __restrict__ bucket,
                                                         const int4* __restrict__ ovf,
                                                         const int* __restrict__ ovf_n,
                                                         const float* __restrict__ b2,
                                                         const float* __restrict__ Wn,
                                                         const float* __restrict__ bn,
                                                         const float* __restrict__ Wr,
                                                         const float* __restrict__ br,
                                                         float* __restrict__ logits,
                                                         float* __restrict__ rr,
                                                         float* __restrict__ part) {
  __shared__ float s[256];
  int l = threadIdx.x & 15;
  int node = blockIdx.x * 16 + (threadIdx.x >> 4);
  float4 acc = gather_node(xw2, cnt, bucket, ovf, ovf_n, node, l);
  float di = dinv[node];
  const float4 b4 = *(const float4*)(b2 + l * 4);
  float4 r;
  r.x = fmaxf(fmaf(acc.x, di, b4.x), 0.f); r.y = fmaxf(fmaf(acc.y, di, b4.y), 0.f);
  r.z = fmaxf(fmaf(acc.z, di, b4.z), 0.f); r.w = fmaxf(fmaf(acc.w, di, b4.w), 0.f);
  const float4 wn4 = *(const float4*)(Wn + l * 4);
  const float4 wr4 = *(const float4*)(Wr + l * 4);
  float an = r.x * wn4.x + r.y * wn4.y + r.z * wn4.z + r.w * wn4.w;
  float ar = r.x * wr4.x + r.y * wr4.y + r.z * wr4.z + r.w * wr4.w;
#pragma unroll
  for (int m = 8; m > 0; m >>= 1) {
    an += __shfl_xor(an, m, 64);
    ar += __shfl_xor(ar, m, 64);
  }
  float lg = an + bn[0];
  if (l == 0) {
    logits[node] = lg;
    float xr = ar + br[0];
    rr[node] = 0.01f / (1.0f + expf(-xr));
  }
  // block max of 16 logits (dups across lanes are harmless)
  s[threadIdx.x] = lg;
  __syncthreads();
  for (int w = 128; w > 0; w >>= 1) {
    if (threadIdx.x < w) s[threadIdx.x] = fmaxf(s[threadIdx.x], s[threadIdx.x + w]);
    __syncthreads();
  }
  if (threadIdx.x == 0) part[blockIdx.x] = s[0];
}

// ---------------- softmax: per-block global-max re-reduce + exp + atomic sum ----------------

__global__ __launch_bounds__(256) void k_sexp(const float* __restrict__ logits,
                                              const float* __restrict__ part,
                                              float* __restrict__ sel,
                                              float* __restrict__ gsum) {
  __shared__ float s[256];
  float m = -INFINITY;
  for (int i = threadIdx.x; i < NTILE; i += 256) m = fmaxf(m, part[i]);
  s[threadIdx.x] = m;
  __syncthreads();
  for (int w = 128; w > 0; w >>= 1) {
    if (threadIdx.x < w) s[threadIdx.x] = fmaxf(s[threadIdx.x], s[threadIdx.x + w]);
    __syncthreads();
  }
  float gm = s[0];
  __syncthreads();
  float acc = 0.0f;
  for (int i = blockIdx.x * 256 + threadIdx.x; i < NN; i += RB * 256) {
    float e = expf(logits[i] - gm);
    sel[i] = e;
    acc += e;
  }
  s[threadIdx.x] = acc;
  __syncthreads();
  for (int w = 128; w > 0; w >>= 1) {
    if (threadIdx.x < w) s[threadIdx.x] += s[threadIdx.x + w];
    __syncthreads();
  }
  if (threadIdx.x == 0) unsafeAtomicAdd(gsum, s[0]);  // 256 funnel atomics ~4us
}

__global__ __launch_bounds__(256) void k_snorm(float* __restrict__ sel,
                                               const float* __restrict__ gsum) {
  int i = blockIdx.x * 256 + threadIdx.x;
  if (i < NN) sel[i] *= (1.0f / gsum[0]);
}

// ---------------- launch ----------------

extern "C" void kernel_launch(void* const* d_in, const int* in_sizes, int n_in,
                              void* d_out, int out_size, void* d_ws, size_t ws_size,
                              hipStream_t stream) {
  const float* x  = (const float*)d_in[0];
  const int*   ei = (const int*)d_in[1];   // [2, E]: src row then dst row
  const float* ew = (const float*)d_in[2];
  const float* W1 = (const float*)d_in[3];
  const float* b1 = (const float*)d_in[4];
  const float* W2 = (const float*)d_in[5];
  const float* b2 = (const float*)d_in[6];
  const float* Wn = (const float*)d_in[7];
  const float* bn = (const float*)d_in[8];
  const float* Wr = (const float*)d_in[9];
  const float* br = (const float*)d_in[10];
  const int* src = ei;
  const int* dst = ei + NE;

  // ws layout (byte offsets, all regions 16B-aligned)
  char* wsb = (char*)d_ws;
  __half* xw     = (__half*)wsb;                        // 12,800,000 B (layer-1 features)
  __half* xw2    = (__half*)(wsb + 12800000);           // 12,800,000 B (layer-2 features)
  float*  dinv   = (float*)(wsb + 25600000);            // 400,000 B
  float*  logits = (float*)(wsb + 26000000);            // 400,000 B
  int2*   bucket = (int2*)(wsb + 26400000);             // 25,600,000 B
  int4*   ovf    = (int4*)(wsb + 52000000);             // 65,536 B
  int*    cnt    = (int*)(wsb + 52065536);              // 400,000 B -- memset from here
  int*    ovf_n  = cnt + NN;                            // 4 B
  float*  gsum   = (float*)(ovf_n + 1);                 // 4 B       -- memset to here
  float*  part1  = gsum + 1;                            // 25,000 B (6250 floats)

  float* sel = (float*)d_out;                           // node_selector [N]
  float* rr  = (float*)d_out + NN;                      // rescue_ratios [N]

  int gN = (NN + 255) / 256;

  // zero cnt + ovf_n + gsum in one memset
  hipMemsetAsync(cnt, 0, (size_t)(NN + 2) * 4, stream);

  // ---- bucket build ----
  k_bucket<<<NEB, 256, 0, stream>>>(src, dst, ew, cnt, bucket, ovf, ovf_n);

  // ---- layer 1 gemm (inline degsum + dinv fold) ----
  k_gemm1_dinv<<<512, 256, 0, stream>>>(x, W1, cnt, bucket, ovf, ovf_n, dinv, xw);

  // ---- fused layer-1 gather (sliced) + gemm2: xw -> xw2 ----
  k_gather_gemm2<<<NTILE, 256, 0, stream>>>(xw, dinv, cnt, bucket, ovf, ovf_n,
                                            b1, W2, xw2);

  // ---- layer 2 gather (sliced) + heads + max partials ----
  k_gather_l2_heads<<<NTILE, 256, 0, stream>>>(xw2, dinv, cnt, bucket, ovf, ovf_n,
                                               b2, Wn, bn, Wr, br, logits, rr, part1);

  // ---- softmax ----
  k_sexp<<<RB, 256, 0, stream>>>(logits, part1, sel, gsum);
  k_snorm<<<gN, 256, 0, stream>>>(sel, gsum);
}

// Round 17
// 254.997 us; speedup vs baseline: 1.6839x; 1.6839x over previous
//
#include <hip/hip_runtime.h>
#include <hip/hip_fp16.h>
#include <math.h>

#define NN 100000
#define NE 1000000
#define CAP 32        // bucket capacity per node; degrees ~Poisson(10), max ~27
#define OVCAP 4096    // overflow list capacity (correct fallback, ~never used)
#define NEB 3907      // ceil(NE/256) bucket blocks
#define NTILE 6250    // NN/16 MFMA row-tiles
#define RB 256        // softmax reduction grid
// H = 64. Features stored fp16 with dinv[src] PRE-FOLDED: xw'[i] = dinv[i]*(X@W)[i].
// Gather: acc = sum_e ew*xw'[src] + xw'[self]; out = acc*dinv[dst].
// R14 LESSON: gather input and GEMM output must be DISTINCT buffers.
// R16 LESSON: src-sliced gather falsified — conditional loads kill the load
// pipeline (dur 2x at identical FETCH). Dense 4-deep unroll is the best form.

typedef _Float16 half8 __attribute__((ext_vector_type(8)));
typedef float f32x4 __attribute__((ext_vector_type(4)));

// ---------------- bucket build (measured floor ~75us; R10 falsified
// placement fixes: writeback = 1 line/edge, temporal) ----------------

__global__ __launch_bounds__(256) void k_bucket(const int* __restrict__ src,
                                                const int* __restrict__ dst,
                                                const float* __restrict__ ew,
                                                int* __restrict__ cnt,
                                                int2* __restrict__ bucket,
                                                int4* __restrict__ ovf,
                                                int* __restrict__ ovf_n) {
  int e = blockIdx.x * 256 + threadIdx.x;
  if (e < NE) {
    int s = src[e];
    int d = dst[e];
    float w = ew[e];
    int pos = atomicAdd(&cnt[d], 1);
    if (pos < CAP) {
      bucket[d * CAP + pos] = make_int2(s, __float_as_int(w));
    } else {
      int t = atomicAdd(ovf_n, 1);
      if (t < OVCAP) ovf[t] = make_int4(s, d, __float_as_int(w), 0);
    }
  }
}

// ---------------- W staging: fragment layout in LDS (k=(s*32+q*8+j), n=t*16+l15) ----------------

__device__ __forceinline__ void stage_B_lds(const float* __restrict__ W,
                                            _Float16* __restrict__ ldsB) {
  for (int u = threadIdx.x; u < 512; u += 256) {
    int slane = u & 63, ts = u >> 6;
    int t = ts >> 1, s = ts & 1;
    int qq = slane >> 4, ll = slane & 15;
#pragma unroll
    for (int j = 0; j < 8; ++j)
      ldsB[u * 8 + j] = (_Float16)W[(s * 32 + qq * 8 + j) * 64 + t * 16 + ll];
  }
}

// ---------------- degsum helper (all lanes; redundant across q-groups) ----------------

__device__ __forceinline__ float degsum_row(const int* __restrict__ cnt,
                                            const int2* __restrict__ bucket,
                                            const int4* __restrict__ ovf,
                                            const int* __restrict__ ovf_n,
                                            int row) {
  int c = cnt[row];
  int cc = c < CAP ? c : CAP;
  float dsum = 1.0f;  // self-loop
  const int2* bk = bucket + (size_t)row * CAP;
  for (int j = 0; j < cc; ++j) dsum += __int_as_float(bk[j].y);
  if (c > CAP) {
    int on = ovf_n[0]; if (on > OVCAP) on = OVCAP;
    for (int t = 0; t < on; ++t) {
      int4 o = ovf[t];
      if (o.y == row) dsum += __int_as_float(o.z);
    }
  }
  return 1.0f / sqrtf(dsum);
}

// ---------------- GEMM1 + inline degsum: dinv + Y' = dinv*(X@W1), fp16 ----------------
// 16x16x32_f16; A: m=lane&15, k=(lane>>4)*8+j; C/D: col=lane&15, row=q*4+reg
// [m89-verified].

__global__ __launch_bounds__(256) void k_gemm1_dinv(const float* __restrict__ X,
                                                    const float* __restrict__ W,
                                                    const int* __restrict__ cnt,
                                                    const int2* __restrict__ bucket,
                                                    const int4* __restrict__ ovf,
                                                    const int* __restrict__ ovf_n,
                                                    float* __restrict__ dinv,
                                                    __half* __restrict__ Y) {
  __shared__ _Float16 ldsB[4096];
  stage_B_lds(W, ldsB);
  __syncthreads();
  int lane = threadIdx.x & 63;
  int l15 = lane & 15, q = lane >> 4;
  half8 bfr[4][2];
#pragma unroll
  for (int t = 0; t < 4; ++t)
#pragma unroll
    for (int s = 0; s < 2; ++s)
      bfr[t][s] = *(half8*)&ldsB[((t * 2 + s) * 64 + lane) * 8];

  int wid = blockIdx.x * 4 + (threadIdx.x >> 6);
  for (int tile = wid; tile < NTILE; tile += 2048) {
    int row = tile * 16 + l15;
    float di = degsum_row(cnt, bucket, ovf, ovf_n, row);
    if (q == 0) dinv[row] = di;
    f32x4 acc[4] = {{0.f,0.f,0.f,0.f},{0.f,0.f,0.f,0.f},
                    {0.f,0.f,0.f,0.f},{0.f,0.f,0.f,0.f}};
#pragma unroll
    for (int s = 0; s < 2; ++s) {
      const float* ap = X + (size_t)row * 64 + s * 32 + q * 8;
      float4 a0 = *(const float4*)ap;
      float4 a1 = *(const float4*)(ap + 4);
      half8 af;
      af[0] = (_Float16)a0.x; af[1] = (_Float16)a0.y;
      af[2] = (_Float16)a0.z; af[3] = (_Float16)a0.w;
      af[4] = (_Float16)a1.x; af[5] = (_Float16)a1.y;
      af[6] = (_Float16)a1.z; af[7] = (_Float16)a1.w;
#pragma unroll
      for (int t = 0; t < 4; ++t)
        acc[t] = __builtin_amdgcn_mfma_f32_16x16x32_f16(af, bfr[t][s], acc[t], 0, 0, 0);
    }
#pragma unroll
    for (int r = 0; r < 4; ++r) {
      int rw = tile * 16 + q * 4 + r;
      float dv = __shfl(di, q * 4 + r, 64);
#pragma unroll
      for (int t = 0; t < 4; ++t)
        Y[(size_t)rw * 64 + t * 16 + l15] = __float2half(acc[t][r] * dv);
    }
  }
}

// ---------------- gather core: 16 lanes/node, fp16 rows, dinv pre-folded ----------------
// Dense 4-deep unconditional unroll (R15 form — best measured).

__device__ __forceinline__ float4 h4load(const __half* p) {
  float2 raw = *(const float2*)p;  // 4 halfs in one dwordx2
  __half2 a = *(__half2*)&raw.x;
  __half2 b = *(__half2*)&raw.y;
  float2 fa = __half22float2(a), fb = __half22float2(b);
  return make_float4(fa.x, fa.y, fb.x, fb.y);
}

__device__ __forceinline__ float4 gather_node(const __half* __restrict__ xw,
                                              const int* __restrict__ cnt,
                                              const int2* __restrict__ bucket,
                                              const int4* __restrict__ ovf,
                                              const int* __restrict__ ovf_n,
                                              int node, int l) {
  int c = cnt[node];
  int cc = c < CAP ? c : CAP;
  const int4* bk4 = (const int4*)(bucket + (size_t)node * CAP);
  float4 acc = make_float4(0.f, 0.f, 0.f, 0.f);

  int j = 0;
  for (; j + 4 <= cc; j += 4) {
    int4 pa = bk4[j >> 1];
    int4 pb = bk4[(j >> 1) + 1];
    const float4 x0 = h4load(xw + (size_t)pa.x * 64 + l * 4);
    const float4 x1 = h4load(xw + (size_t)pa.z * 64 + l * 4);
    const float4 x2 = h4load(xw + (size_t)pb.x * 64 + l * 4);
    const float4 x3 = h4load(xw + (size_t)pb.z * 64 + l * 4);
    float v0 = __int_as_float(pa.y);
    float v1 = __int_as_float(pa.w);
    float v2 = __int_as_float(pb.y);
    float v3 = __int_as_float(pb.w);
    acc.x = fmaf(x0.x, v0, acc.x); acc.y = fmaf(x0.y, v0, acc.y);
    acc.z = fmaf(x0.z, v0, acc.z); acc.w = fmaf(x0.w, v0, acc.w);
    acc.x = fmaf(x1.x, v1, acc.x); acc.y = fmaf(x1.y, v1, acc.y);
    acc.z = fmaf(x1.z, v1, acc.z); acc.w = fmaf(x1.w, v1, acc.w);
    acc.x = fmaf(x2.x, v2, acc.x); acc.y = fmaf(x2.y, v2, acc.y);
    acc.z = fmaf(x2.z, v2, acc.z); acc.w = fmaf(x2.w, v2, acc.w);
    acc.x = fmaf(x3.x, v3, acc.x); acc.y = fmaf(x3.y, v3, acc.y);
    acc.z = fmaf(x3.z, v3, acc.z); acc.w = fmaf(x3.w, v3, acc.w);
  }
  const int2* bk = (const int2*)bk4;
  for (; j < cc; ++j) {
    int2 E = bk[j];
    const float4 xa = h4load(xw + (size_t)E.x * 64 + l * 4);
    float v = __int_as_float(E.y);
    acc.x = fmaf(xa.x, v, acc.x); acc.y = fmaf(xa.y, v, acc.y);
    acc.z = fmaf(xa.z, v, acc.z); acc.w = fmaf(xa.w, v, acc.w);
  }
  if (c > CAP) {
    int on = ovf_n[0]; if (on > OVCAP) on = OVCAP;
    for (int t = 0; t < on; ++t) {
      int4 o = ovf[t];
      if (o.y == node) {
        const float4 xa = h4load(xw + (size_t)o.x * 64 + l * 4);
        float v = __int_as_float(o.z);
        acc.x = fmaf(xa.x, v, acc.x); acc.y = fmaf(xa.y, v, acc.y);
        acc.z = fmaf(xa.z, v, acc.z); acc.w = fmaf(xa.w, v, acc.w);
      }
    }
  }
  // self-loop: xw'[self] weight 1 (outer *dinv[dst] completes dinv^2)
  const float4 xs = h4load(xw + (size_t)node * 64 + l * 4);
  acc.x += xs.x; acc.y += xs.y; acc.z += xs.z; acc.w += xs.w;
  return acc;
}

// ---------------- fused layer-1 gather + GEMM2 (xw -> xw2) ----------------

__global__ __launch_bounds__(256) void k_gather_gemm2(const __half* __restrict__ xw,
                                                      const float* __restrict__ dinv,
                                                      const int* __restrict__ cnt,
                                                      const int2* __restrict__ bucket,
                                                      const int4* __restrict__ ovf,
                                                      const int* __restrict__ ovf_n,
                                                      const float* __restrict__ b1,
                                                      const float* __restrict__ W2,
                                                      __half* __restrict__ Y) {
  __shared__ _Float16 ldsB[4096];
  __shared__ _Float16 ldsR[16 * 72];
  __shared__ float sdi[16];
  stage_B_lds(W2, ldsB);

  int l = threadIdx.x & 15;
  int g = threadIdx.x >> 4;
  int node = blockIdx.x * 16 + g;
  float4 acc = gather_node(xw, cnt, bucket, ovf, ovf_n, node, l);
  float di = dinv[node];
  const float4 b4 = *(const float4*)(b1 + l * 4);
  _Float16* rp = &ldsR[g * 72 + l * 4];
  rp[0] = (_Float16)fmaxf(fmaf(acc.x, di, b4.x), 0.f);
  rp[1] = (_Float16)fmaxf(fmaf(acc.y, di, b4.y), 0.f);
  rp[2] = (_Float16)fmaxf(fmaf(acc.z, di, b4.z), 0.f);
  rp[3] = (_Float16)fmaxf(fmaf(acc.w, di, b4.w), 0.f);
  if (l == 0) sdi[g] = di;
  __syncthreads();

  int lane = threadIdx.x & 63;
  int l15 = lane & 15, q = lane >> 4;
  int t = threadIdx.x >> 6;  // this wave's col-tile
  half8 a0 = *(half8*)&ldsR[l15 * 72 + q * 8];
  half8 a1 = *(half8*)&ldsR[l15 * 72 + 32 + q * 8];
  half8 bf0 = *(half8*)&ldsB[((t * 2 + 0) * 64 + lane) * 8];
  half8 bf1 = *(half8*)&ldsB[((t * 2 + 1) * 64 + lane) * 8];
  f32x4 acc2 = {0.f, 0.f, 0.f, 0.f};
  acc2 = __builtin_amdgcn_mfma_f32_16x16x32_f16(a0, bf0, acc2, 0, 0, 0);
  acc2 = __builtin_amdgcn_mfma_f32_16x16x32_f16(a1, bf1, acc2, 0, 0, 0);
#pragma unroll
  for (int r = 0; r < 4; ++r) {
    int rw = blockIdx.x * 16 + q * 4 + r;
    float dv = sdi[q * 4 + r];
    Y[(size_t)rw * 64 + t * 16 + l15] = __float2half(acc2[r] * dv);
  }
}

// ---------------- layer-2 aggregation + heads + per-block max partial ----------------

__global__ __launch_bounds__(256) void k_gather_l2_heads(const __half* __restrict__ xw2,
                                                         const float* __restrict__ dinv,
                                                         const int* __restrict__ cnt,
                                                         const int2* __restrict__ bucket,
                                                         const int4* __restrict__ ovf,
                                                         const int* __restrict__ ovf_n,
                                                         const float* __restrict__ b2,
                                                         const float* __restrict__ Wn,
                                                         const float* __restrict__ bn,
                                                         const float* __restrict__ Wr,
                                                         const float* __restrict__ br,
                                                         float* __restrict__ logits,
                                                         float* __restrict__ rr,
                                                         float* __restrict__ part) {
  __shared__ float s[256];
  int l = threadIdx.x & 15;
  int node = blockIdx.x * 16 + (threadIdx.x >> 4);
  float4 acc = gather_node(xw2, cnt, bucket, ovf, ovf_n, node, l);
  float di = dinv[node];
  const float4 b4 = *(const float4*)(b2 + l * 4);
  float4 r;
  r.x = fmaxf(fmaf(acc.x, di, b4.x), 0.f); r.y = fmaxf(fmaf(acc.y, di, b4.y), 0.f);
  r.z = fmaxf(fmaf(acc.z, di, b4.z), 0.f); r.w = fmaxf(fmaf(acc.w, di, b4.w), 0.f);
  const float4 wn4 = *(const float4*)(Wn + l * 4);
  const float4 wr4 = *(const float4*)(Wr + l * 4);
  float an = r.x * wn4.x + r.y * wn4.y + r.z * wn4.z + r.w * wn4.w;
  float ar = r.x * wr4.x + r.y * wr4.y + r.z * wr4.z + r.w * wr4.w;
#pragma unroll
  for (int m = 8; m > 0; m >>= 1) {
    an += __shfl_xor(an, m, 64);
    ar += __shfl_xor(ar, m, 64);
  }
  float lg = an + bn[0];
  if (l == 0) {
    logits[node] = lg;
    float xr = ar + br[0];
    rr[node] = 0.01f / (1.0f + expf(-xr));
  }
  // block max of 16 logits (dups across lanes are harmless)
  s[threadIdx.x] = lg;
  __syncthreads();
  for (int w = 128; w > 0; w >>= 1) {
    if (threadIdx.x < w) s[threadIdx.x] = fmaxf(s[threadIdx.x], s[threadIdx.x + w]);
    __syncthreads();
  }
  if (threadIdx.x == 0) part[blockIdx.x] = s[0];
}

// ---------------- softmax: per-block global-max re-reduce + exp + atomic sum ----------------

__global__ __launch_bounds__(256) void k_sexp(const float* __restrict__ logits,
                                              const float* __restrict__ part,
                                              float* __restrict__ sel,
                                              float* __restrict__ gsum) {
  __shared__ float s[256];
  float m = -INFINITY;
  for (int i = threadIdx.x; i < NTILE; i += 256) m = fmaxf(m, part[i]);
  s[threadIdx.x] = m;
  __syncthreads();
  for (int w = 128; w > 0; w >>= 1) {
    if (threadIdx.x < w) s[threadIdx.x] = fmaxf(s[threadIdx.x], s[threadIdx.x + w]);
    __syncthreads();
  }
  float gm = s[0];
  __syncthreads();
  float acc = 0.0f;
  for (int i = blockIdx.x * 256 + threadIdx.x; i < NN; i += RB * 256) {
    float e = expf(logits[i] - gm);
    sel[i] = e;
    acc += e;
  }
  s[threadIdx.x] = acc;
  __syncthreads();
  for (int w = 128; w > 0; w >>= 1) {
    if (threadIdx.x < w) s[threadIdx.x] += s[threadIdx.x + w];
    __syncthreads();
  }
  if (threadIdx.x == 0) unsafeAtomicAdd(gsum, s[0]);  // 256 funnel atomics ~4us
}

__global__ __launch_bounds__(256) void k_snorm(float* __restrict__ sel,
                                               const float* __restrict__ gsum) {
  int i = blockIdx.x * 256 + threadIdx.x;
  if (i < NN) sel[i] *= (1.0f / gsum[0]);
}

// ---------------- launch ----------------

extern "C" void kernel_launch(void* const* d_in, const int* in_sizes, int n_in,
                              void* d_out, int out_size, void* d_ws, size_t ws_size,
                              hipStream_t stream) {
  const float* x  = (const float*)d_in[0];
  const int*   ei = (const int*)d_in[1];   // [2, E]: src row then dst row
  const float* ew = (const float*)d_in[2];
  const float* W1 = (const float*)d_in[3];
  const float* b1 = (const float*)d_in[4];
  const float* W2 = (const float*)d_in[5];
  const float* b2 = (const float*)d_in[6];
  const float* Wn = (const float*)d_in[7];
  const float* bn = (const float*)d_in[8];
  const float* Wr = (const float*)d_in[9];
  const float* br = (const float*)d_in[10];
  const int* src = ei;
  const int* dst = ei + NE;

  // ws layout (byte offsets, all regions 16B-aligned)
  char* wsb = (char*)d_ws;
  __half* xw     = (__half*)wsb;                        // 12,800,000 B (layer-1 features)
  __half* xw2    = (__half*)(wsb + 12800000);           // 12,800,000 B (layer-2 features)
  float*  dinv   = (float*)(wsb + 25600000);            // 400,000 B
  float*  logits = (float*)(wsb + 26000000);            // 400,000 B
  int2*   bucket = (int2*)(wsb + 26400000);             // 25,600,000 B
  int4*   ovf    = (int4*)(wsb + 52000000);             // 65,536 B
  int*    cnt    = (int*)(wsb + 52065536);              // 400,000 B -- memset from here
  int*    ovf_n  = cnt + NN;                            // 4 B
  float*  gsum   = (float*)(ovf_n + 1);                 // 4 B       -- memset to here
  float*  part1  = gsum + 1;                            // 25,000 B (6250 floats)

  float* sel = (float*)d_out;                           // node_selector [N]
  float* rr  = (float*)d_out + NN;                      // rescue_ratios [N]

  int gN = (NN + 255) / 256;

  // zero cnt + ovf_n + gsum in one memset
  hipMemsetAsync(cnt, 0, (size_t)(NN + 2) * 4, stream);

  // ---- bucket build ----
  k_bucket<<<NEB, 256, 0, stream>>>(src, dst, ew, cnt, bucket, ovf, ovf_n);

  // ---- layer 1 gemm (inline degsum + dinv fold) ----
  k_gemm1_dinv<<<512, 256, 0, stream>>>(x, W1, cnt, bucket, ovf, ovf_n, dinv, xw);

  // ---- fused layer-1 gather + gemm2: xw -> xw2 (h never hits global) ----
  k_gather_gemm2<<<NTILE, 256, 0, stream>>>(xw, dinv, cnt, bucket, ovf, ovf_n,
                                            b1, W2, xw2);

  // ---- layer 2 gather + heads + max partials ----
  k_gather_l2_heads<<<NTILE, 256, 0, stream>>>(xw2, dinv, cnt, bucket, ovf, ovf_n,
                                               b2, Wn, bn, Wr, br, logits, rr, part1);

  // ---- softmax ----
  k_sexp<<<RB, 256, 0, stream>>>(logits, part1, sel, gsum);
  k_snorm<<<gN, 256, 0, stream>>>(sel, gsum);
}